// Round 16
// baseline (167.780 us; speedup 1.0000x reference)
//
#include <hip/hip_runtime.h>
#include <hip/hip_bf16.h>

using short8 = __attribute__((ext_vector_type(8))) short;
using f32x4  = __attribute__((ext_vector_type(4))) float;

constexpr int BSZ = 8192;
constexpr int DD  = 512;
constexpr int NC  = 100;
constexpr int NT  = 64;                 // 128-row tiles per dim
constexpr int NBLK = NT * (NT + 1) / 2; // 2080 upper-triangle blocks (= 8*260)
constexpr float INV_T = 1.0f / 0.07f;   // analytic shift m = 1/T

static __device__ __forceinline__ ushort f2bf(float x) {
    union { float f; unsigned u; } c; c.f = x;
    unsigned r = c.u + 0x7fffu + ((c.u >> 16) & 1u);   // RNE
    return (ushort)(r >> 16);
}
static __device__ __forceinline__ float bf2f(ushort u) {
    union { unsigned u; float f; } c; c.u = ((unsigned)u) << 16; return c.f;
}

#define DPPADD(v, ctrl) { \
    int _x = __builtin_amdgcn_update_dpp(0, __float_as_int(v), ctrl, 0xf, 0xf, true); \
    v += __int_as_float(_x); }
#define ROWSUM16(v) { DPPADD(v, 0x128) DPPADD(v, 0x124) DPPADD(v, 0x122) DPPADD(v, 0x121) }

// ---------- kernel 1: L2-normalize rows, fp32 -> bf16 ----------
__global__ __launch_bounds__(256) void norm_rows(const float* __restrict__ feat,
                                                 ushort* __restrict__ fnrm) {
    const int row = blockIdx.x * 4 + (threadIdx.x >> 6);
    const int l   = threadIdx.x & 63;
    const float4* src = reinterpret_cast<const float4*>(feat + (size_t)row * DD);
    float4 v0 = src[l * 2 + 0];
    float4 v1 = src[l * 2 + 1];
    float ss = v0.x*v0.x + v0.y*v0.y + v0.z*v0.z + v0.w*v0.w
             + v1.x*v1.x + v1.y*v1.y + v1.z*v1.z + v1.w*v1.w;
    #pragma unroll
    for (int m = 32; m >= 1; m >>= 1) ss += __shfl_xor(ss, m, 64);
    const float rn = rsqrtf(ss);
    float vals[8] = {v0.x, v0.y, v0.z, v0.w, v1.x, v1.y, v1.z, v1.w};
    ushort u[8];
    #pragma unroll
    for (int j = 0; j < 8; ++j) u[j] = f2bf(vals[j] * rn);
    *reinterpret_cast<short8*>(fnrm + (size_t)row * DD + l * 8) =
        *reinterpret_cast<short8*>(u);
}

// ---------- kernel 2: per-class g_c via ballot scan -> cls_val[c], counts[c] ----
// (verified R13/R14) Sum_pos identity: sum_i spos_i/npos_i = (||g_c||^2-n)/(T(n-1))
__global__ __launch_bounds__(256) void gsum(const ushort* __restrict__ fnrm,
                                            const int* __restrict__ labels,
                                            float* __restrict__ cls_val,
                                            int* __restrict__ counts) {
    __shared__ int   slab[BSZ];          // 32 KB
    __shared__ float gred[4][DD];        // 8 KB
    __shared__ float sq4[4];
    __shared__ int   cc[4];

    const int t = threadIdx.x, w = t >> 6, lam = t & 63;
    for (int i = t; i < BSZ; i += 256) slab[i] = labels[i];
    __syncthreads();

    const int c = blockIdx.x;
    float a[8] = {0.f,0.f,0.f,0.f,0.f,0.f,0.f,0.f};
    int cnt = 0;
    for (int base = w * 2048; base < (w + 1) * 2048; base += 64) {
        const unsigned long long m0 = __ballot(slab[base + lam] == c);
        cnt += (int)__popcll(m0);
        unsigned long long m = m0;
        while (m) {
            const int j = __ffsll((long long)m) - 1; m &= m - 1;
            const short8 v = *reinterpret_cast<const short8*>(
                fnrm + (size_t)(base + j) * DD + lam * 8);
            #pragma unroll
            for (int d = 0; d < 8; ++d) a[d] += bf2f((ushort)v[d]);
        }
    }
    #pragma unroll
    for (int d = 0; d < 8; ++d) gred[w][lam * 8 + d] = a[d];
    if (lam == 0) cc[w] = cnt;
    __syncthreads();

    const float g0 = gred[0][t] + gred[1][t] + gred[2][t] + gred[3][t];
    const float g1 = gred[0][t + 256] + gred[1][t + 256] + gred[2][t + 256] + gred[3][t + 256];
    float sq = g0 * g0 + g1 * g1;
    #pragma unroll
    for (int m = 32; m >= 1; m >>= 1) sq += __shfl_xor(sq, m, 64);
    if (lam == 0) sq4[w] = sq;
    __syncthreads();
    if (t == 0) {
        const float gsq = sq4[0] + sq4[1] + sq4[2] + sq4[3];
        const int   n   = cc[0] + cc[1] + cc[2] + cc[3];
        counts[c]  = n;
        cls_val[c] = (n >= 2) ? (gsq - (float)n) * INV_T / (float)(n - 1) : 0.f;
    }
}

// ---------- kernel 3: sim-GEMM -> denom. PURE-GLOBAL fragments, no LDS K-loop ----
// 4 waves (2x2), wave = 64x64 out (acc[4][4] = 64 AGPR). 16 K-tiles of 32.
// Each lane loads its MFMA frags straight from global (fnrm L2/L3-resident):
// 8 x global_load_dwordx4 with imm offsets + 16 MFMA per iter; frag double-
// buffer; compiler emits counted vmcnt. No barriers, no staging, waves free-run.
__global__ __launch_bounds__(256, 3) void supcon_main(const ushort* __restrict__ fnrm,
                                                      float* __restrict__ part_denom) {
    __shared__ float red[256];            // [128 row][2 wc]
    __shared__ float cred[256];           // [128 col][2 wr]

    // bijective XCD-contiguous swizzle (2080 = 8 * 260) + upper-tri decode
    const int raw = blockIdx.x;
    const int bid = (raw & 7) * 260 + (raw >> 3);
    int rt = 0, rem = bid;
    while (rem >= NT - rt) { rem -= NT - rt; ++rt; }
    const int ct = rt + rem;
    const bool diag = (ct == rt);

    const int t  = threadIdx.x;
    const int l  = t & 63;
    const int lr = l & 15, grp = l >> 4;
    const int w  = t >> 6;
    const int wr = w >> 1, wc = w & 1;    // 2x2 wave grid; wave = 64x64 out
    const int rowBase = rt * 128, colBase = ct * 128;

    // per-lane fragment base pointers (k=0): frag fa covers rows +fa*16
    // lane reads row (base + fa*16 + lr), elems grp*8.. (16B)
    const short8* pa0 = reinterpret_cast<const short8*>(
        fnrm + (size_t)(rowBase + wr * 64 +  0 + lr) * DD + grp * 8);
    const short8* pa1 = reinterpret_cast<const short8*>(
        fnrm + (size_t)(rowBase + wr * 64 + 16 + lr) * DD + grp * 8);
    const short8* pa2 = reinterpret_cast<const short8*>(
        fnrm + (size_t)(rowBase + wr * 64 + 32 + lr) * DD + grp * 8);
    const short8* pa3 = reinterpret_cast<const short8*>(
        fnrm + (size_t)(rowBase + wr * 64 + 48 + lr) * DD + grp * 8);
    const short8* pb0 = reinterpret_cast<const short8*>(
        fnrm + (size_t)(colBase + wc * 64 +  0 + lr) * DD + grp * 8);
    const short8* pb1 = reinterpret_cast<const short8*>(
        fnrm + (size_t)(colBase + wc * 64 + 16 + lr) * DD + grp * 8);
    const short8* pb2 = reinterpret_cast<const short8*>(
        fnrm + (size_t)(colBase + wc * 64 + 32 + lr) * DD + grp * 8);
    const short8* pb3 = reinterpret_cast<const short8*>(
        fnrm + (size_t)(colBase + wc * 64 + 48 + lr) * DD + grp * 8);

    f32x4 acc[4][4];
    #pragma unroll
    for (int i = 0; i < 4; ++i)
        #pragma unroll
        for (int j = 0; j < 4; ++j) acc[i][j] = f32x4{0.f, 0.f, 0.f, 0.f};

    // k-tile kt -> element offset kt*32 -> short8 index kt*4 (imm-foldable)
    short8 a0[4], b0[4], a1[4], b1[4];
    #define LOADF(B, KT) { \
        a##B[0] = pa0[(KT) * 4]; a##B[1] = pa1[(KT) * 4]; \
        a##B[2] = pa2[(KT) * 4]; a##B[3] = pa3[(KT) * 4]; \
        b##B[0] = pb0[(KT) * 4]; b##B[1] = pb1[(KT) * 4]; \
        b##B[2] = pb2[(KT) * 4]; b##B[3] = pb3[(KT) * 4]; }
    #define MFMAS(B) { \
        _Pragma("unroll") \
        for (int fa = 0; fa < 4; ++fa) \
            _Pragma("unroll") \
            for (int fb = 0; fb < 4; ++fb) \
                acc[fa][fb] = __builtin_amdgcn_mfma_f32_16x16x32_bf16( \
                    a##B[fa], b##B[fb], acc[fa][fb], 0, 0, 0); }

    LOADF(0, 0)
    #pragma unroll
    for (int it2 = 0; it2 < 8; ++it2) {
        const int k0 = it2 * 2;
        LOADF(1, k0 + 1)                  // prefetch odd tile while buf0 computes
        MFMAS(0)
        if (k0 + 2 < 16) LOADF(0, k0 + 2) // prefetch next even tile
        MFMAS(1)
    }
    #undef LOADF
    #undef MFMAS

    // ---- lean epilogue: e = exp(sim - m); row & col denom sums only ----
    float cdv[4] = {0.f, 0.f, 0.f, 0.f};
    #pragma unroll
    for (int fa = 0; fa < 4; ++fa) {
        #pragma unroll
        for (int r = 0; r < 4; ++r) {
            const int row_l = wr * 64 + fa * 16 + grp * 4 + r;
            const int grow  = rowBase + row_l;
            float dsum = 0.f;
            #pragma unroll
            for (int fb = 0; fb < 4; ++fb) {
                const int col_l = wc * 64 + fb * 16 + lr;
                const float e  = __expf(acc[fa][fb][r] * INV_T - INV_T);
                const float ev = ((colBase + col_l) != grow) ? e : 0.f;
                dsum += ev; cdv[fb] += ev;
            }
            ROWSUM16(dsum)
            if (lr == 0) red[row_l * 2 + wc] = dsum;
        }
    }
    #pragma unroll
    for (int fb = 0; fb < 4; ++fb) {      // col-side: reduce over grp lanes
        cdv[fb] += __shfl_xor(cdv[fb], 16, 64);
        cdv[fb] += __shfl_xor(cdv[fb], 32, 64);
    }
    if (grp == 0) {
        #pragma unroll
        for (int fb = 0; fb < 4; ++fb)
            cred[(wc * 64 + fb * 16 + lr) * 2 + wr] = cdv[fb];
    }
    __syncthreads();
    if (t < 128) {                        // row-side: combine 2 wc halves
        const float d = red[t * 2] + red[t * 2 + 1];
        part_denom[(size_t)ct * BSZ + rowBase + t] = d;
    } else if (!diag) {                   // col-side: combine 2 wr halves
        const int c = t - 128;
        const float d = cred[c * 2] + cred[c * 2 + 1];
        part_denom[(size_t)rt * BSZ + colBase + c] = d;
    }
}

// ---------- kernel 4: per-row lse + per-block scalar partials ----------
__global__ __launch_bounds__(256) void row_finalize(const float* __restrict__ part_denom,
                                                    const int* __restrict__ counts,
                                                    const int* __restrict__ labels,
                                                    float* __restrict__ bsum,
                                                    float* __restrict__ bval) {
    __shared__ float s4[4], v4[4];
    const int t = threadIdx.x;
    const int row = blockIdx.x * 256 + t;
    float denom = 0.f;
    for (int k = 0; k < NT; ++k) denom += part_denom[(size_t)k * BSZ + row];
    const bool valid = counts[labels[row]] >= 2;
    float s = valid ? (INV_T + logf(denom + 1e-12f)) : 0.f;
    float v = valid ? 1.f : 0.f;
    #pragma unroll
    for (int m = 32; m >= 1; m >>= 1) { s += __shfl_xor(s, m, 64); v += __shfl_xor(v, m, 64); }
    if ((t & 63) == 0) { s4[t >> 6] = s; v4[t >> 6] = v; }
    __syncthreads();
    if (t == 0) {
        bsum[blockIdx.x] = s4[0] + s4[1] + s4[2] + s4[3];
        bval[blockIdx.x] = v4[0] + v4[1] + v4[2] + v4[3];
    }
}

// ---------- kernel 5: final scalar ----------
__global__ __launch_bounds__(128) void final_reduce(const float* __restrict__ bsum,
                                                    const float* __restrict__ bval,
                                                    const float* __restrict__ cls_val,
                                                    float* __restrict__ out) {
    __shared__ float r2[2], q2[2], p2[2];
    const int t = threadIdx.x;
    float s = (t < 32) ? bsum[t] : 0.f;
    float v = (t < 32) ? bval[t] : 0.f;
    float p = (t < NC) ? cls_val[t] : 0.f;
    #pragma unroll
    for (int m = 32; m >= 1; m >>= 1) {
        s += __shfl_xor(s, m, 64); v += __shfl_xor(v, m, 64); p += __shfl_xor(p, m, 64);
    }
    if ((t & 63) == 0) { r2[t >> 6] = s; q2[t >> 6] = v; p2[t >> 6] = p; }
    __syncthreads();
    if (t == 0) {
        const float S = r2[0] + r2[1], V = q2[0] + q2[1], SP = p2[0] + p2[1];
        out[0] = -(SP - S) / fmaxf(V, 1.f);
    }
}

extern "C" void kernel_launch(void* const* d_in, const int* in_sizes, int n_in,
                              void* d_out, int out_size, void* d_ws, size_t ws_size,
                              hipStream_t stream) {
    const float* feat   = (const float*)d_in[0];
    const int*   labels = (const int*)d_in[1];
    float*       out    = (float*)d_out;

    char* ws = (char*)d_ws;
    ushort* fnrm       = (ushort*)ws;  ws += (size_t)BSZ * DD * 2;   // 8 MB
    float*  part_denom = (float*)ws;   ws += (size_t)NT * BSZ * 4;   // 2 MB
    float*  cls_val    = (float*)ws;   ws += NC * 4 + 288;
    int*    counts     = (int*)ws;     ws += NC * 4 + 288;
    float*  bsum       = (float*)ws;   ws += 32 * 4;
    float*  bval       = (float*)ws;   ws += 32 * 4;

    hipLaunchKernelGGL(norm_rows,    dim3(BSZ / 4), dim3(256),  0, stream, feat, fnrm);
    hipLaunchKernelGGL(gsum,         dim3(NC),      dim3(256),  0, stream,
                       fnrm, labels, cls_val, counts);
    hipLaunchKernelGGL(supcon_main,  dim3(NBLK),    dim3(256),  0, stream,
                       fnrm, part_denom);
    hipLaunchKernelGGL(row_finalize, dim3(BSZ/256), dim3(256),  0, stream,
                       part_denom, counts, labels, bsum, bval);
    hipLaunchKernelGGL(final_reduce, dim3(1),       dim3(128),  0, stream,
                       bsum, bval, cls_val, out);
}

// Round 17
// 82.279 us; speedup vs baseline: 2.0392x; 2.0392x over previous
//
#include <hip/hip_runtime.h>
#include <hip/hip_bf16.h>

using short8 = __attribute__((ext_vector_type(8))) short;
using f32x4  = __attribute__((ext_vector_type(4))) float;

constexpr int BSZ = 8192;
constexpr int DD  = 512;
constexpr int NC  = 100;
constexpr int NT  = 64;                 // 128-row tiles per dim
constexpr int NBLK = NT * (NT + 1) / 2; // 2080 upper-triangle blocks (= 8*260)
constexpr float INV_T = 1.0f / 0.07f;   // analytic shift m = 1/T

static __device__ __forceinline__ ushort f2bf(float x) {
    union { float f; unsigned u; } c; c.f = x;
    unsigned r = c.u + 0x7fffu + ((c.u >> 16) & 1u);   // RNE
    return (ushort)(r >> 16);
}
static __device__ __forceinline__ float bf2f(ushort u) {
    union { unsigned u; float f; } c; c.u = ((unsigned)u) << 16; return c.f;
}

static __device__ __forceinline__ void gload16(const void* g, void* l) {
    __builtin_amdgcn_global_load_lds((const __attribute__((address_space(1))) void*)g,
                                     (__attribute__((address_space(3))) void*)l, 16, 0, 0);
}

// asm ds_read_b128: opaque to compiler waitcnt insertion (counted pipeline survives)
#define DSR(dst, addr, imm) \
    asm volatile("ds_read_b128 %0, %1 offset:%2" : "=v"(dst) : "v"(addr), "i"(imm));

#define DPPADD(v, ctrl) { \
    int _x = __builtin_amdgcn_update_dpp(0, __float_as_int(v), ctrl, 0xf, 0xf, true); \
    v += __int_as_float(_x); }
#define ROWSUM16(v) { DPPADD(v, 0x128) DPPADD(v, 0x124) DPPADD(v, 0x122) DPPADD(v, 0x121) }

// ---------- kernel 1: L2-normalize rows, fp32 -> bf16 ----------
__global__ __launch_bounds__(256) void norm_rows(const float* __restrict__ feat,
                                                 ushort* __restrict__ fnrm) {
    const int row = blockIdx.x * 4 + (threadIdx.x >> 6);
    const int l   = threadIdx.x & 63;
    const float4* src = reinterpret_cast<const float4*>(feat + (size_t)row * DD);
    float4 v0 = src[l * 2 + 0];
    float4 v1 = src[l * 2 + 1];
    float ss = v0.x*v0.x + v0.y*v0.y + v0.z*v0.z + v0.w*v0.w
             + v1.x*v1.x + v1.y*v1.y + v1.z*v1.z + v1.w*v1.w;
    #pragma unroll
    for (int m = 32; m >= 1; m >>= 1) ss += __shfl_xor(ss, m, 64);
    const float rn = rsqrtf(ss);
    float vals[8] = {v0.x, v0.y, v0.z, v0.w, v1.x, v1.y, v1.z, v1.w};
    ushort u[8];
    #pragma unroll
    for (int j = 0; j < 8; ++j) u[j] = f2bf(vals[j] * rn);
    *reinterpret_cast<short8*>(fnrm + (size_t)row * DD + l * 8) =
        *reinterpret_cast<short8*>(u);
}

// ---------- kernel 2: per-class g_c via ballot scan -> cls_val[c], counts[c] ----
// (verified R13-R15) Sum_pos identity: sum_i spos_i/npos_i = (||g_c||^2-n)/(T(n-1))
__global__ __launch_bounds__(256) void gsum(const ushort* __restrict__ fnrm,
                                            const int* __restrict__ labels,
                                            float* __restrict__ cls_val,
                                            int* __restrict__ counts) {
    __shared__ int   slab[BSZ];          // 32 KB
    __shared__ float gred[4][DD];        // 8 KB
    __shared__ float sq4[4];
    __shared__ int   cc[4];

    const int t = threadIdx.x, w = t >> 6, lam = t & 63;
    for (int i = t; i < BSZ; i += 256) slab[i] = labels[i];
    __syncthreads();

    const int c = blockIdx.x;
    float a[8] = {0.f,0.f,0.f,0.f,0.f,0.f,0.f,0.f};
    int cnt = 0;
    for (int base = w * 2048; base < (w + 1) * 2048; base += 64) {
        const unsigned long long m0 = __ballot(slab[base + lam] == c);
        cnt += (int)__popcll(m0);
        unsigned long long m = m0;
        while (m) {
            const int j = __ffsll((long long)m) - 1; m &= m - 1;
            const short8 v = *reinterpret_cast<const short8*>(
                fnrm + (size_t)(base + j) * DD + lam * 8);
            #pragma unroll
            for (int d = 0; d < 8; ++d) a[d] += bf2f((ushort)v[d]);
        }
    }
    #pragma unroll
    for (int d = 0; d < 8; ++d) gred[w][lam * 8 + d] = a[d];
    if (lam == 0) cc[w] = cnt;
    __syncthreads();

    const float g0 = gred[0][t] + gred[1][t] + gred[2][t] + gred[3][t];
    const float g1 = gred[0][t + 256] + gred[1][t + 256] + gred[2][t + 256] + gred[3][t + 256];
    float sq = g0 * g0 + g1 * g1;
    #pragma unroll
    for (int m = 32; m >= 1; m >>= 1) sq += __shfl_xor(sq, m, 64);
    if (lam == 0) sq4[w] = sq;
    __syncthreads();
    if (t == 0) {
        const float gsq = sq4[0] + sq4[1] + sq4[2] + sq4[3];
        const int   n   = cc[0] + cc[1] + cc[2] + cc[3];
        counts[c]  = n;
        cls_val[c] = (n >= 2) ? (gsq - (float)n) * INV_T / (float)(n - 1) : 0.f;
    }
}

// ---------- kernel 3: sim-GEMM -> denom only. 2-buf, 4 blocks/CU (R15) ----------
// 4 waves (2x2), wave = 64x64 out (acc[4][4] = 64 AGPR). BK=32, 16 K-tiles.
// 2 LDS bufs (32 KB) -> 4 blocks/CU. Per iter: vmcnt(0)+barrier (tile it,
// staged one full iter earlier, landed) -> STG(it+1) -> ds_read -> MFMA.
__global__ __launch_bounds__(256, 4) void supcon_main(const ushort* __restrict__ fnrm,
                                                      float* __restrict__ part_denom) {
    __shared__ __align__(16) ushort smem[2 * 8192];    // 32 KB: buf b at b*16384B

    // bijective XCD-contiguous swizzle (2080 = 8 * 260) + upper-tri decode
    const int raw = blockIdx.x;
    const int bid = (raw & 7) * 260 + (raw >> 3);
    int rt = 0, rem = bid;
    while (rem >= NT - rt) { rem -= NT - rt; ++rt; }
    const int ct = rt + rem;
    const bool diag = (ct == rt);

    const int t  = threadIdx.x;
    const int l  = t & 63;
    const int lr = l & 15, grp = l >> 4;
    const int w  = t >> 6;
    const int wr = w >> 1, wc = w & 1;    // 2x2 wave grid; wave = 64x64 out
    const int rowBase = rt * 128, colBase = ct * 128;

    // staging: thread t fills phys chunk t (rows 0-63) and t+256 (rows 64-127).
    // logical chunk = pc ^ ((row>>1)&3), invariant under row+64; applied by
    // pre-swizzling the global source (LDS dest stays linear).
    const int srow = t >> 2;
    const int slc  = (t & 3) ^ ((srow >> 1) & 3);
    const ushort* gA = fnrm + (size_t)(rowBase + srow) * DD + slc * 8;
    const ushort* gB = fnrm + (size_t)(colBase + srow) * DD + slc * 8;
    char* S = (char*)smem;
    const int t16 = t * 16;

    #define STG(kt, b) { \
        gload16(gA + (kt) * 32,           S + (b) * 16384 +         t16); \
        gload16(gA + (kt) * 32 + 64 * DD, S + (b) * 16384 +  4096 + t16); \
        gload16(gB + (kt) * 32,           S + (b) * 16384 +  8192 + t16); \
        gload16(gB + (kt) * 32 + 64 * DD, S + (b) * 16384 + 12288 + t16); }

    // ds_read byte addrs (loop-invariant); buf & frag are immediates.
    const int swz = ((grp ^ ((lr >> 1) & 3)) << 4);
    const int va  = (wr * 64 + lr) * 64 + swz;          // + b*16384 + fa*1024
    const int vb  = 8192 + (wc * 64 + lr) * 64 + swz;   // + b*16384 + fb*1024

    f32x4 acc[4][4];
    #pragma unroll
    for (int i = 0; i < 4; ++i)
        #pragma unroll
        for (int j = 0; j < 4; ++j) acc[i][j] = f32x4{0.f, 0.f, 0.f, 0.f};

    STG(0, 0)

    #pragma unroll
    for (int it = 0; it < 16; ++it) {
        const int b = it & 1;
        asm volatile("s_waitcnt vmcnt(0)" ::: "memory");  // tile it landed
        __builtin_amdgcn_s_barrier();                     // ...for all waves
        if (it < 15) STG(it + 1, b ^ 1)                   // full-iter issue->wait gap

        short8 aF[4], bF[4];
        DSR(aF[0], va, (b * 16384) + 0)     DSR(aF[1], va, (b * 16384) + 1024)
        DSR(aF[2], va, (b * 16384) + 2048)  DSR(aF[3], va, (b * 16384) + 3072)
        DSR(bF[0], vb, (b * 16384) + 0)     DSR(bF[1], vb, (b * 16384) + 1024)
        DSR(bF[2], vb, (b * 16384) + 2048)  DSR(bF[3], vb, (b * 16384) + 3072)
        asm volatile("s_waitcnt lgkmcnt(0)");
        __builtin_amdgcn_sched_barrier(0);   // rule #18
        __builtin_amdgcn_s_setprio(1);
        #pragma unroll
        for (int fa = 0; fa < 4; ++fa)
            #pragma unroll
            for (int fb = 0; fb < 4; ++fb)
                acc[fa][fb] = __builtin_amdgcn_mfma_f32_16x16x32_bf16(
                    aF[fa], bF[fb], acc[fa][fb], 0, 0, 0);
        __builtin_amdgcn_s_setprio(0);
    }
    #undef STG

    // ---- lean epilogue: e = exp(sim - m); row & col denom sums only ----
    __syncthreads();
    float* red  = reinterpret_cast<float*>(smem);          // [128 row][2 wc]
    float* cred = reinterpret_cast<float*>(smem) + 256;    // [128 col][2 wr]

    float cdv[4] = {0.f, 0.f, 0.f, 0.f};
    #pragma unroll
    for (int fa = 0; fa < 4; ++fa) {
        #pragma unroll
        for (int r = 0; r < 4; ++r) {
            const int row_l = wr * 64 + fa * 16 + grp * 4 + r;
            const int grow  = rowBase + row_l;
            float dsum = 0.f;
            #pragma unroll
            for (int fb = 0; fb < 4; ++fb) {
                const int col_l = wc * 64 + fb * 16 + lr;
                const float e  = __expf(acc[fa][fb][r] * INV_T - INV_T);
                const float ev = ((colBase + col_l) != grow) ? e : 0.f;
                dsum += ev; cdv[fb] += ev;
            }
            ROWSUM16(dsum)
            if (lr == 0) red[row_l * 2 + wc] = dsum;
        }
    }
    #pragma unroll
    for (int fb = 0; fb < 4; ++fb) {      // col-side: reduce over grp lanes
        cdv[fb] += __shfl_xor(cdv[fb], 16, 64);
        cdv[fb] += __shfl_xor(cdv[fb], 32, 64);
    }
    if (grp == 0) {
        #pragma unroll
        for (int fb = 0; fb < 4; ++fb)
            cred[(wc * 64 + fb * 16 + lr) * 2 + wr] = cdv[fb];
    }
    __syncthreads();
    if (t < 128) {                        // row-side: combine 2 wc halves
        const float d = red[t * 2] + red[t * 2 + 1];
        part_denom[(size_t)ct * BSZ + rowBase + t] = d;
    } else if (!diag) {                   // col-side: combine 2 wr halves
        const int c = t - 128;
        const float d = cred[c * 2] + cred[c * 2 + 1];
        part_denom[(size_t)rt * BSZ + colBase + c] = d;
    }
}

// ---------- kernel 4: fused finalize (row lse partials + last-block reduce) ----
__global__ __launch_bounds__(256) void finalize(const float* __restrict__ part_denom,
                                               const int* __restrict__ counts,
                                               const int* __restrict__ labels,
                                               const float* __restrict__ cls_val,
                                               float* __restrict__ bsum,
                                               float* __restrict__ bval,
                                               int* __restrict__ ticket,
                                               float* __restrict__ out) {
    __shared__ float s4[4], v4[4];
    __shared__ int last;
    const int t = threadIdx.x;
    const int row = blockIdx.x * 256 + t;
    float denom = 0.f;
    for (int k = 0; k < NT; ++k) denom += part_denom[(size_t)k * BSZ + row];
    const bool valid = counts[labels[row]] >= 2;
    float s = valid ? (INV_T + logf(denom + 1e-12f)) : 0.f;
    float v = valid ? 1.f : 0.f;
    #pragma unroll
    for (int m = 32; m >= 1; m >>= 1) { s += __shfl_xor(s, m, 64); v += __shfl_xor(v, m, 64); }
    if ((t & 63) == 0) { s4[t >> 6] = s; v4[t >> 6] = v; }
    __syncthreads();
    if (t == 0) {
        bsum[blockIdx.x] = s4[0] + s4[1] + s4[2] + s4[3];
        bval[blockIdx.x] = v4[0] + v4[1] + v4[2] + v4[3];
        __threadfence();
        last = (atomicAdd(ticket, 1) == gridDim.x - 1) ? 1 : 0;
    }
    __syncthreads();
    if (last) {                            // exactly one block reaches here
        __threadfence();                   // acquire: see all blocks' partials
        float ss = (t < 32) ? bsum[t] : 0.f;
        float vv = (t < 32) ? bval[t] : 0.f;
        float pp = (t < NC) ? cls_val[t] : 0.f;
        #pragma unroll
        for (int m = 32; m >= 1; m >>= 1) {
            ss += __shfl_xor(ss, m, 64); vv += __shfl_xor(vv, m, 64);
            pp += __shfl_xor(pp, m, 64);
        }
        if ((t & 63) == 0) { s4[t >> 6] = ss; v4[t >> 6] = vv; }
        __shared__ float p4[4];
        if ((t & 63) == 0) p4[t >> 6] = pp;
        __syncthreads();
        if (t == 0) {
            const float S  = s4[0] + s4[1] + s4[2] + s4[3];
            const float V  = v4[0] + v4[1] + v4[2] + v4[3];
            const float SP = p4[0] + p4[1] + p4[2] + p4[3];
            out[0] = -(SP - S) / fmaxf(V, 1.f);
        }
    }
}

extern "C" void kernel_launch(void* const* d_in, const int* in_sizes, int n_in,
                              void* d_out, int out_size, void* d_ws, size_t ws_size,
                              hipStream_t stream) {
    const float* feat   = (const float*)d_in[0];
    const int*   labels = (const int*)d_in[1];
    float*       out    = (float*)d_out;

    char* ws = (char*)d_ws;
    ushort* fnrm       = (ushort*)ws;  ws += (size_t)BSZ * DD * 2;   // 8 MB
    float*  part_denom = (float*)ws;   ws += (size_t)NT * BSZ * 4;   // 2 MB
    float*  cls_val    = (float*)ws;   ws += NC * 4 + 288;
    int*    counts     = (int*)ws;     ws += NC * 4 + 288;
    float*  bsum       = (float*)ws;   ws += 32 * 4;
    float*  bval       = (float*)ws;   ws += 32 * 4;
    int*    ticket     = (int*)ws;     ws += 256;

    hipMemsetAsync(ticket, 0, sizeof(int), stream);
    hipLaunchKernelGGL(norm_rows,    dim3(BSZ / 4), dim3(256),  0, stream, feat, fnrm);
    hipLaunchKernelGGL(gsum,         dim3(NC),      dim3(256),  0, stream,
                       fnrm, labels, cls_val, counts);
    hipLaunchKernelGGL(supcon_main,  dim3(NBLK),    dim3(256),  0, stream,
                       fnrm, part_denom);
    hipLaunchKernelGGL(finalize,     dim3(BSZ/256), dim3(256),  0, stream,
                       part_denom, counts, labels, cls_val, bsum, bval, ticket, out);
}

// Round 18
// 76.507 us; speedup vs baseline: 2.1930x; 1.0754x over previous
//
#include <hip/hip_runtime.h>
#include <hip/hip_bf16.h>

using short8 = __attribute__((ext_vector_type(8))) short;
using f32x4  = __attribute__((ext_vector_type(4))) float;

constexpr int BSZ = 8192;
constexpr int DD  = 512;
constexpr int NC  = 100;
constexpr int NT  = 64;                 // 128-row tiles per dim
constexpr int NBLK = NT * (NT + 1) / 2; // 2080 upper-triangle blocks (= 8*260)
constexpr float INV_T = 1.0f / 0.07f;   // analytic shift m = 1/T

static __device__ __forceinline__ ushort f2bf(float x) {
    union { float f; unsigned u; } c; c.f = x;
    unsigned r = c.u + 0x7fffu + ((c.u >> 16) & 1u);   // RNE
    return (ushort)(r >> 16);
}
static __device__ __forceinline__ float bf2f(ushort u) {
    union { unsigned u; float f; } c; c.u = ((unsigned)u) << 16; return c.f;
}

static __device__ __forceinline__ void gload16(const void* g, void* l) {
    __builtin_amdgcn_global_load_lds((const __attribute__((address_space(1))) void*)g,
                                     (__attribute__((address_space(3))) void*)l, 16, 0, 0);
}

// asm ds_read_b128: opaque to compiler waitcnt insertion (counted pipeline survives)
#define DSR(dst, addr, imm) \
    asm volatile("ds_read_b128 %0, %1 offset:%2" : "=v"(dst) : "v"(addr), "i"(imm));

#define DPPADD(v, ctrl) { \
    int _x = __builtin_amdgcn_update_dpp(0, __float_as_int(v), ctrl, 0xf, 0xf, true); \
    v += __int_as_float(_x); }
#define ROWSUM16(v) { DPPADD(v, 0x128) DPPADD(v, 0x124) DPPADD(v, 0x122) DPPADD(v, 0x121) }

// ---------- kernel 1: L2-normalize rows, fp32 -> bf16 ----------
__global__ __launch_bounds__(256) void norm_rows(const float* __restrict__ feat,
                                                 ushort* __restrict__ fnrm) {
    const int row = blockIdx.x * 4 + (threadIdx.x >> 6);
    const int l   = threadIdx.x & 63;
    const float4* src = reinterpret_cast<const float4*>(feat + (size_t)row * DD);
    float4 v0 = src[l * 2 + 0];
    float4 v1 = src[l * 2 + 1];
    float ss = v0.x*v0.x + v0.y*v0.y + v0.z*v0.z + v0.w*v0.w
             + v1.x*v1.x + v1.y*v1.y + v1.z*v1.z + v1.w*v1.w;
    #pragma unroll
    for (int m = 32; m >= 1; m >>= 1) ss += __shfl_xor(ss, m, 64);
    const float rn = rsqrtf(ss);
    float vals[8] = {v0.x, v0.y, v0.z, v0.w, v1.x, v1.y, v1.z, v1.w};
    ushort u[8];
    #pragma unroll
    for (int j = 0; j < 8; ++j) u[j] = f2bf(vals[j] * rn);
    *reinterpret_cast<short8*>(fnrm + (size_t)row * DD + l * 8) =
        *reinterpret_cast<short8*>(u);
}

// ---------- kernel 2: per-class g_c via ballot scan -> cls_val[c], counts[c] ----
// (verified R13-R15) Sum_pos identity: sum_i spos_i/npos_i = (||g_c||^2-n)/(T(n-1))
__global__ __launch_bounds__(256) void gsum(const ushort* __restrict__ fnrm,
                                            const int* __restrict__ labels,
                                            float* __restrict__ cls_val,
                                            int* __restrict__ counts) {
    __shared__ int   slab[BSZ];          // 32 KB
    __shared__ float gred[4][DD];        // 8 KB
    __shared__ float sq4[4];
    __shared__ int   cc[4];

    const int t = threadIdx.x, w = t >> 6, lam = t & 63;
    for (int i = t; i < BSZ; i += 256) slab[i] = labels[i];
    __syncthreads();

    const int c = blockIdx.x;
    float a[8] = {0.f,0.f,0.f,0.f,0.f,0.f,0.f,0.f};
    int cnt = 0;
    for (int base = w * 2048; base < (w + 1) * 2048; base += 64) {
        const unsigned long long m0 = __ballot(slab[base + lam] == c);
        cnt += (int)__popcll(m0);
        unsigned long long m = m0;
        while (m) {
            const int j = __ffsll((long long)m) - 1; m &= m - 1;
            const short8 v = *reinterpret_cast<const short8*>(
                fnrm + (size_t)(base + j) * DD + lam * 8);
            #pragma unroll
            for (int d = 0; d < 8; ++d) a[d] += bf2f((ushort)v[d]);
        }
    }
    #pragma unroll
    for (int d = 0; d < 8; ++d) gred[w][lam * 8 + d] = a[d];
    if (lam == 0) cc[w] = cnt;
    __syncthreads();

    const float g0 = gred[0][t] + gred[1][t] + gred[2][t] + gred[3][t];
    const float g1 = gred[0][t + 256] + gred[1][t + 256] + gred[2][t + 256] + gred[3][t + 256];
    float sq = g0 * g0 + g1 * g1;
    #pragma unroll
    for (int m = 32; m >= 1; m >>= 1) sq += __shfl_xor(sq, m, 64);
    if (lam == 0) sq4[w] = sq;
    __syncthreads();
    if (t == 0) {
        const float gsq = sq4[0] + sq4[1] + sq4[2] + sq4[3];
        const int   n   = cc[0] + cc[1] + cc[2] + cc[3];
        counts[c]  = n;
        cls_val[c] = (n >= 2) ? (gsq - (float)n) * INV_T / (float)(n - 1) : 0.f;
    }
}

// ---------- kernel 3: sim-GEMM -> denom only. 2-buf, 4 blocks/CU (R15) ----------
// 4 waves (2x2), wave = 64x64 out (acc[4][4] = 64 AGPR). BK=32, 16 K-tiles.
// 2 LDS bufs (32 KB) -> 4 blocks/CU. Per iter: vmcnt(0)+barrier (tile it,
// staged one full iter earlier, landed) -> STG(it+1) -> ds_read -> MFMA.
// launch_bounds(256,4): arch VGPR <= 64 (+64 acc = 128/wave at 4 waves/SIMD).
__global__ __launch_bounds__(256, 4) void supcon_main(const ushort* __restrict__ fnrm,
                                                      float* __restrict__ part_denom) {
    __shared__ __align__(16) ushort smem[2 * 8192];    // 32 KB: buf b at b*16384B

    // bijective XCD-contiguous swizzle (2080 = 8 * 260) + upper-tri decode
    const int raw = blockIdx.x;
    const int bid = (raw & 7) * 260 + (raw >> 3);
    int rt = 0, rem = bid;
    while (rem >= NT - rt) { rem -= NT - rt; ++rt; }
    const int ct = rt + rem;
    const bool diag = (ct == rt);

    const int t  = threadIdx.x;
    const int l  = t & 63;
    const int lr = l & 15, grp = l >> 4;
    const int w  = t >> 6;
    const int wr = w >> 1, wc = w & 1;    // 2x2 wave grid; wave = 64x64 out
    const int rowBase = rt * 128, colBase = ct * 128;

    // staging: thread t fills phys chunk t (rows 0-63) and t+256 (rows 64-127).
    // logical chunk = pc ^ ((row>>1)&3), invariant under row+64; applied by
    // pre-swizzling the global source (LDS dest stays linear).
    const int srow = t >> 2;
    const int slc  = (t & 3) ^ ((srow >> 1) & 3);
    const ushort* gA = fnrm + (size_t)(rowBase + srow) * DD + slc * 8;
    const ushort* gB = fnrm + (size_t)(colBase + srow) * DD + slc * 8;
    char* S = (char*)smem;
    const int t16 = t * 16;

    #define STG(kt, b) { \
        gload16(gA + (kt) * 32,           S + (b) * 16384 +         t16); \
        gload16(gA + (kt) * 32 + 64 * DD, S + (b) * 16384 +  4096 + t16); \
        gload16(gB + (kt) * 32,           S + (b) * 16384 +  8192 + t16); \
        gload16(gB + (kt) * 32 + 64 * DD, S + (b) * 16384 + 12288 + t16); }

    // ds_read byte addrs (loop-invariant); buf & frag are immediates.
    const int swz = ((grp ^ ((lr >> 1) & 3)) << 4);
    const int va  = (wr * 64 + lr) * 64 + swz;          // + b*16384 + fa*1024
    const int vb  = 8192 + (wc * 64 + lr) * 64 + swz;   // + b*16384 + fb*1024

    f32x4 acc[4][4];
    #pragma unroll
    for (int i = 0; i < 4; ++i)
        #pragma unroll
        for (int j = 0; j < 4; ++j) acc[i][j] = f32x4{0.f, 0.f, 0.f, 0.f};

    STG(0, 0)

    #pragma unroll
    for (int it = 0; it < 16; ++it) {
        const int b = it & 1;
        asm volatile("s_waitcnt vmcnt(0)" ::: "memory");  // tile it landed
        __builtin_amdgcn_s_barrier();                     // ...for all waves
        if (it < 15) STG(it + 1, b ^ 1)                   // full-iter issue->wait gap

        short8 aF[4], bF[4];
        DSR(aF[0], va, (b * 16384) + 0)     DSR(aF[1], va, (b * 16384) + 1024)
        DSR(aF[2], va, (b * 16384) + 2048)  DSR(aF[3], va, (b * 16384) + 3072)
        DSR(bF[0], vb, (b * 16384) + 0)     DSR(bF[1], vb, (b * 16384) + 1024)
        DSR(bF[2], vb, (b * 16384) + 2048)  DSR(bF[3], vb, (b * 16384) + 3072)
        asm volatile("s_waitcnt lgkmcnt(0)");
        __builtin_amdgcn_sched_barrier(0);   // rule #18
        __builtin_amdgcn_s_setprio(1);
        #pragma unroll
        for (int fa = 0; fa < 4; ++fa)
            #pragma unroll
            for (int fb = 0; fb < 4; ++fb)
                acc[fa][fb] = __builtin_amdgcn_mfma_f32_16x16x32_bf16(
                    aF[fa], bF[fb], acc[fa][fb], 0, 0, 0);
        __builtin_amdgcn_s_setprio(0);
    }
    #undef STG

    // ---- lean epilogue: e = exp(sim - m); row & col denom sums only ----
    __syncthreads();
    float* red  = reinterpret_cast<float*>(smem);          // [128 row][2 wc]
    float* cred = reinterpret_cast<float*>(smem) + 256;    // [128 col][2 wr]

    float cdv[4] = {0.f, 0.f, 0.f, 0.f};
    #pragma unroll
    for (int fa = 0; fa < 4; ++fa) {
        #pragma unroll
        for (int r = 0; r < 4; ++r) {
            const int row_l = wr * 64 + fa * 16 + grp * 4 + r;
            const int grow  = rowBase + row_l;
            float dsum = 0.f;
            #pragma unroll
            for (int fb = 0; fb < 4; ++fb) {
                const int col_l = wc * 64 + fb * 16 + lr;
                const float e  = __expf(acc[fa][fb][r] * INV_T - INV_T);
                const float ev = ((colBase + col_l) != grow) ? e : 0.f;
                dsum += ev; cdv[fb] += ev;
            }
            ROWSUM16(dsum)
            if (lr == 0) red[row_l * 2 + wc] = dsum;
        }
    }
    #pragma unroll
    for (int fb = 0; fb < 4; ++fb) {      // col-side: reduce over grp lanes
        cdv[fb] += __shfl_xor(cdv[fb], 16, 64);
        cdv[fb] += __shfl_xor(cdv[fb], 32, 64);
    }
    if (grp == 0) {
        #pragma unroll
        for (int fb = 0; fb < 4; ++fb)
            cred[(wc * 64 + fb * 16 + lr) * 2 + wr] = cdv[fb];
    }
    __syncthreads();
    if (t < 128) {                        // row-side: combine 2 wc halves
        const float d = red[t * 2] + red[t * 2 + 1];
        part_denom[(size_t)ct * BSZ + rowBase + t] = d;
    } else if (!diag) {                   // col-side: combine 2 wr halves
        const int c = t - 128;
        const float d = cred[c * 2] + cred[c * 2 + 1];
        part_denom[(size_t)rt * BSZ + colBase + c] = d;
    }
}

// ---------- kernel 4: per-row lse + per-block scalar partials ----------
__global__ __launch_bounds__(256) void row_finalize(const float* __restrict__ part_denom,
                                                    const int* __restrict__ counts,
                                                    const int* __restrict__ labels,
                                                    float* __restrict__ bsum,
                                                    float* __restrict__ bval) {
    __shared__ float s4[4], v4[4];
    const int t = threadIdx.x;
    const int row = blockIdx.x * 256 + t;
    float denom = 0.f;
    for (int k = 0; k < NT; ++k) denom += part_denom[(size_t)k * BSZ + row];
    const bool valid = counts[labels[row]] >= 2;
    float s = valid ? (INV_T + logf(denom + 1e-12f)) : 0.f;
    float v = valid ? 1.f : 0.f;
    #pragma unroll
    for (int m = 32; m >= 1; m >>= 1) { s += __shfl_xor(s, m, 64); v += __shfl_xor(v, m, 64); }
    if ((t & 63) == 0) { s4[t >> 6] = s; v4[t >> 6] = v; }
    __syncthreads();
    if (t == 0) {
        bsum[blockIdx.x] = s4[0] + s4[1] + s4[2] + s4[3];
        bval[blockIdx.x] = v4[0] + v4[1] + v4[2] + v4[3];
    }
}

// ---------- kernel 5: final scalar ----------
__global__ __launch_bounds__(128) void final_reduce(const float* __restrict__ bsum,
                                                    const float* __restrict__ bval,
                                                    const float* __restrict__ cls_val,
                                                    float* __restrict__ out) {
    __shared__ float r2[2], q2[2], p2[2];
    const int t = threadIdx.x;
    float s = (t < 32) ? bsum[t] : 0.f;
    float v = (t < 32) ? bval[t] : 0.f;
    float p = (t < NC) ? cls_val[t] : 0.f;
    #pragma unroll
    for (int m = 32; m >= 1; m >>= 1) {
        s += __shfl_xor(s, m, 64); v += __shfl_xor(v, m, 64); p += __shfl_xor(p, m, 64);
    }
    if ((t & 63) == 0) { r2[t >> 6] = s; q2[t >> 6] = v; p2[t >> 6] = p; }
    __syncthreads();
    if (t == 0) {
        const float S = r2[0] + r2[1], V = q2[0] + q2[1], SP = p2[0] + p2[1];
        out[0] = -(SP - S) / fmaxf(V, 1.f);
    }
}

extern "C" void kernel_launch(void* const* d_in, const int* in_sizes, int n_in,
                              void* d_out, int out_size, void* d_ws, size_t ws_size,
                              hipStream_t stream) {
    const float* feat   = (const float*)d_in[0];
    const int*   labels = (const int*)d_in[1];
    float*       out    = (float*)d_out;

    char* ws = (char*)d_ws;
    ushort* fnrm       = (ushort*)ws;  ws += (size_t)BSZ * DD * 2;   // 8 MB
    float*  part_denom = (float*)ws;   ws += (size_t)NT * BSZ * 4;   // 2 MB
    float*  cls_val    = (float*)ws;   ws += NC * 4 + 288;
    int*    counts     = (int*)ws;     ws += NC * 4 + 288;
    float*  bsum       = (float*)ws;   ws += 32 * 4;
    float*  bval       = (float*)ws;   ws += 32 * 4;

    hipLaunchKernelGGL(norm_rows,    dim3(BSZ / 4), dim3(256),  0, stream, feat, fnrm);
    hipLaunchKernelGGL(gsum,         dim3(NC),      dim3(256),  0, stream,
                       fnrm, labels, cls_val, counts);
    hipLaunchKernelGGL(supcon_main,  dim3(NBLK),    dim3(256),  0, stream,
                       fnrm, part_denom);
    hipLaunchKernelGGL(row_finalize, dim3(BSZ/256), dim3(256),  0, stream,
                       part_denom, counts, labels, bsum, bval);
    hipLaunchKernelGGL(final_reduce, dim3(1),       dim3(128),  0, stream,
                       bsum, bval, cls_val, out);
}

// Round 19
// 68.492 us; speedup vs baseline: 2.4496x; 1.1170x over previous
//
#include <hip/hip_runtime.h>
#include <hip/hip_bf16.h>

using short8 = __attribute__((ext_vector_type(8))) short;
using f32x4  = __attribute__((ext_vector_type(4))) float;
typedef long long i64f;
typedef unsigned char uchar;

constexpr int BSZ = 8192;
constexpr int DD  = 512;
constexpr int NC  = 100;
constexpr int NT  = 64;                 // 128-row tiles per dim
constexpr int NBLK = NT * (NT + 1) / 2; // 2080 upper-triangle blocks (= 8*260)
constexpr float INV_T = 1.0f / 0.07f;   // analytic shift m = 1/T

static __device__ __forceinline__ void gload16(const void* g, void* l) {
    __builtin_amdgcn_global_load_lds((const __attribute__((address_space(1))) void*)g,
                                     (__attribute__((address_space(3))) void*)l, 16, 0, 0);
}

// asm ds_read: opaque to compiler waitcnt insertion (counted pipeline survives)
#define DSR64(dst, addr, imm) \
    asm volatile("ds_read_b64 %0, %1 offset:%2" : "=v"(dst) : "v"(addr), "i"(imm));

#define DPPADD(v, ctrl) { \
    int _x = __builtin_amdgcn_update_dpp(0, __float_as_int(v), ctrl, 0xf, 0xf, true); \
    v += __int_as_float(_x); }
#define ROWSUM16(v) { DPPADD(v, 0x128) DPPADD(v, 0x124) DPPADD(v, 0x122) DPPADD(v, 0x121) }

// ---------- kernel 1: L2-normalize rows, fp32 -> fp8 e4m3 (HW cvt, RNE) ----------
__global__ __launch_bounds__(256) void norm_rows(const float* __restrict__ feat,
                                                 uchar* __restrict__ fnrm8) {
    const int row = blockIdx.x * 4 + (threadIdx.x >> 6);
    const int l   = threadIdx.x & 63;
    const float4* src = reinterpret_cast<const float4*>(feat + (size_t)row * DD);
    float4 v0 = src[l * 2 + 0];
    float4 v1 = src[l * 2 + 1];
    float ss = v0.x*v0.x + v0.y*v0.y + v0.z*v0.z + v0.w*v0.w
             + v1.x*v1.x + v1.y*v1.y + v1.z*v1.z + v1.w*v1.w;
    #pragma unroll
    for (int m = 32; m >= 1; m >>= 1) ss += __shfl_xor(ss, m, 64);
    const float rn = rsqrtf(ss);
    int w0 = __builtin_amdgcn_cvt_pk_fp8_f32(v0.x * rn, v0.y * rn, 0,  false);
    w0     = __builtin_amdgcn_cvt_pk_fp8_f32(v0.z * rn, v0.w * rn, w0, true);
    int w1 = __builtin_amdgcn_cvt_pk_fp8_f32(v1.x * rn, v1.y * rn, 0,  false);
    w1     = __builtin_amdgcn_cvt_pk_fp8_f32(v1.z * rn, v1.w * rn, w1, true);
    uint2 q; q.x = (unsigned)w0; q.y = (unsigned)w1;
    *reinterpret_cast<uint2*>(fnrm8 + (size_t)row * DD + l * 8) = q;
}

// ---------- kernel 2: per-class g_c via ballot scan -> cls_val[c], counts[c] ----
// (identity verified R13-R15) sum_i spos_i/npos_i = (||g_c||^2-n)/(T(n-1))
__global__ __launch_bounds__(256) void gsum(const uchar* __restrict__ fnrm8,
                                            const int* __restrict__ labels,
                                            float* __restrict__ cls_val,
                                            int* __restrict__ counts) {
    __shared__ int   slab[BSZ];          // 32 KB
    __shared__ float gred[4][DD];        // 8 KB
    __shared__ float sq4[4];
    __shared__ int   cc[4];

    const int t = threadIdx.x, w = t >> 6, lam = t & 63;
    for (int i = t; i < BSZ; i += 256) slab[i] = labels[i];
    __syncthreads();

    const int c = blockIdx.x;
    float a[8] = {0.f,0.f,0.f,0.f,0.f,0.f,0.f,0.f};
    int cnt = 0;
    for (int base = w * 2048; base < (w + 1) * 2048; base += 64) {
        const unsigned long long m0 = __ballot(slab[base + lam] == c);
        cnt += (int)__popcll(m0);
        unsigned long long m = m0;
        while (m) {
            const int j = __ffsll((long long)m) - 1; m &= m - 1;
            const uint2 q = *reinterpret_cast<const uint2*>(
                fnrm8 + (size_t)(base + j) * DD + lam * 8);
            a[0] += __builtin_amdgcn_cvt_f32_fp8(q.x, 0);
            a[1] += __builtin_amdgcn_cvt_f32_fp8(q.x, 1);
            a[2] += __builtin_amdgcn_cvt_f32_fp8(q.x, 2);
            a[3] += __builtin_amdgcn_cvt_f32_fp8(q.x, 3);
            a[4] += __builtin_amdgcn_cvt_f32_fp8(q.y, 0);
            a[5] += __builtin_amdgcn_cvt_f32_fp8(q.y, 1);
            a[6] += __builtin_amdgcn_cvt_f32_fp8(q.y, 2);
            a[7] += __builtin_amdgcn_cvt_f32_fp8(q.y, 3);
        }
    }
    #pragma unroll
    for (int d = 0; d < 8; ++d) gred[w][lam * 8 + d] = a[d];
    if (lam == 0) cc[w] = cnt;
    __syncthreads();

    const float g0 = gred[0][t] + gred[1][t] + gred[2][t] + gred[3][t];
    const float g1 = gred[0][t + 256] + gred[1][t + 256] + gred[2][t + 256] + gred[3][t + 256];
    float sq = g0 * g0 + g1 * g1;
    #pragma unroll
    for (int m = 32; m >= 1; m >>= 1) sq += __shfl_xor(sq, m, 64);
    if (lam == 0) sq4[w] = sq;
    __syncthreads();
    if (t == 0) {
        const float gsq = sq4[0] + sq4[1] + sq4[2] + sq4[3];
        const int   n   = cc[0] + cc[1] + cc[2] + cc[3];
        counts[c]  = n;
        cls_val[c] = (n >= 2) ? (gsq - (float)n) * INV_T / (float)(n - 1) : 0.f;
    }
}

// ---------- kernel 3: fp8 sim-GEMM -> denom. 3-buf depth-2, 4 blocks/CU ----------
// 4 waves (2x2), wave = 64x64 out (acc[4][4] = 64 AGPR). BK=32 (fp8), 16 K-tiles.
// 3 LDS bufs x 8KB (A 4K + B 4K) = 24 KB -> 4 blocks/CU AND depth-2 vmcnt(2).
// Per iter: vmcnt(2) [tile it landed, it+1 in flight] -> barrier -> STG(it+2)
// -> 8 ds_read_b64 -> lgkm0 -> 16 MFMA fp8 (K=32 each, same rate as bf16).
__global__ __launch_bounds__(256, 4) void supcon_main(const uchar* __restrict__ fnrm8,
                                                      float* __restrict__ part_denom) {
    __shared__ __align__(16) uchar smem[3 * 8192];     // 24 KB: buf b at b*8192B

    // bijective XCD-contiguous swizzle (2080 = 8 * 260) + upper-tri decode
    const int raw = blockIdx.x;
    const int bid = (raw & 7) * 260 + (raw >> 3);
    int rt = 0, rem = bid;
    while (rem >= NT - rt) { rem -= NT - rt; ++rt; }
    const int ct = rt + rem;
    const bool diag = (ct == rt);

    const int t  = threadIdx.x;
    const int l  = t & 63;
    const int lr = l & 15, grp = l >> 4;
    const int w  = t >> 6;
    const int wr = w >> 1, wc = w & 1;    // 2x2 wave grid; wave = 64x64 out
    const int rowBase = rt * 128, colBase = ct * 128;

    // staging: tile = [128 rows][32 B]; thread t owns 16B pair (row t>>1, p=t&1).
    // 8B-slot swizzle slot^ = slot ^ (((row>>2)&1)<<1) moves whole 16B pairs:
    // logical pair lp = p ^ ((row>>2)&1). Pre-swizzled global source; LDS linear.
    const int srow = t >> 1;
    const int lp   = (t & 1) ^ ((srow >> 2) & 1);
    const uchar* g8A = fnrm8 + (size_t)(rowBase + srow) * DD + lp * 16;
    const uchar* g8B = fnrm8 + (size_t)(colBase + srow) * DD + lp * 16;
    uchar* S = smem;
    const int t16 = t * 16;

    #define STG(kt, b) { \
        gload16(g8A + (kt) * 32, S + (b) * 8192 +        t16); \
        gload16(g8B + (kt) * 32, S + (b) * 8192 + 4096 + t16); }

    // ds_read byte addrs (loop-invariant); buf & frag are immediates.
    // frag fa: row = wr*64 + fa*16 + lr; slot = grp ^ (((lr>>2)&1)<<1)
    const int slot = grp ^ (((lr >> 2) & 1) << 1);
    const int va = (wr * 64 + lr) * 32 + slot * 8;          // + b*8192 + fa*512
    const int vb = 4096 + (wc * 64 + lr) * 32 + slot * 8;   // + b*8192 + fb*512

    f32x4 acc[4][4];
    #pragma unroll
    for (int i = 0; i < 4; ++i)
        #pragma unroll
        for (int j = 0; j < 4; ++j) acc[i][j] = f32x4{0.f, 0.f, 0.f, 0.f};

    STG(0, 0)
    STG(1, 1)

    #pragma unroll
    for (int it = 0; it < 16; ++it) {
        const int b = it % 3;
        if (it < 15) { asm volatile("s_waitcnt vmcnt(2)" ::: "memory"); }
        else         { asm volatile("s_waitcnt vmcnt(0)" ::: "memory"); }
        __builtin_amdgcn_s_barrier();     // tile 'it' fully in LDS for all waves
        if (it < 14) {
            const int nb = (it + 2) % 3;  // overwrites buf of tile it-1 (reads done)
            STG(it + 2, nb)
        }

        i64f aF[4], bF[4];
        DSR64(aF[0], va, (b * 8192) + 0)     DSR64(aF[1], va, (b * 8192) + 512)
        DSR64(aF[2], va, (b * 8192) + 1024)  DSR64(aF[3], va, (b * 8192) + 1536)
        DSR64(bF[0], vb, (b * 8192) + 0)     DSR64(bF[1], vb, (b * 8192) + 512)
        DSR64(bF[2], vb, (b * 8192) + 1024)  DSR64(bF[3], vb, (b * 8192) + 1536)
        asm volatile("s_waitcnt lgkmcnt(0)");
        __builtin_amdgcn_sched_barrier(0);   // rule #18
        __builtin_amdgcn_s_setprio(1);
        #pragma unroll
        for (int fa = 0; fa < 4; ++fa)
            #pragma unroll
            for (int fb = 0; fb < 4; ++fb)
                acc[fa][fb] = __builtin_amdgcn_mfma_f32_16x16x32_fp8_fp8(
                    aF[fa], bF[fb], acc[fa][fb], 0, 0, 0);
        __builtin_amdgcn_s_setprio(0);
    }
    #undef STG

    // ---- lean epilogue: e = exp(sim - m); row & col denom sums only ----
    __syncthreads();
    float* red  = reinterpret_cast<float*>(smem);          // [128 row][2 wc]
    float* cred = reinterpret_cast<float*>(smem) + 256;    // [128 col][2 wr]

    float cdv[4] = {0.f, 0.f, 0.f, 0.f};
    #pragma unroll
    for (int fa = 0; fa < 4; ++fa) {
        #pragma unroll
        for (int r = 0; r < 4; ++r) {
            const int row_l = wr * 64 + fa * 16 + grp * 4 + r;
            const int grow  = rowBase + row_l;
            float dsum = 0.f;
            #pragma unroll
            for (int fb = 0; fb < 4; ++fb) {
                const int col_l = wc * 64 + fb * 16 + lr;
                const float e  = __expf(acc[fa][fb][r] * INV_T - INV_T);
                const float ev = ((colBase + col_l) != grow) ? e : 0.f;
                dsum += ev; cdv[fb] += ev;
            }
            ROWSUM16(dsum)
            if (lr == 0) red[row_l * 2 + wc] = dsum;
        }
    }
    #pragma unroll
    for (int fb = 0; fb < 4; ++fb) {      // col-side: reduce over grp lanes
        cdv[fb] += __shfl_xor(cdv[fb], 16, 64);
        cdv[fb] += __shfl_xor(cdv[fb], 32, 64);
    }
    if (grp == 0) {
        #pragma unroll
        for (int fb = 0; fb < 4; ++fb)
            cred[(wc * 64 + fb * 16 + lr) * 2 + wr] = cdv[fb];
    }
    __syncthreads();
    if (t < 128) {                        // row-side: combine 2 wc halves
        const float d = red[t * 2] + red[t * 2 + 1];
        part_denom[(size_t)ct * BSZ + rowBase + t] = d;
    } else if (!diag) {                   // col-side: combine 2 wr halves
        const int c = t - 128;
        const float d = cred[c * 2] + cred[c * 2 + 1];
        part_denom[(size_t)rt * BSZ + colBase + c] = d;
    }
}

// ---------- kernel 4: per-row lse + per-block scalar partials ----------
__global__ __launch_bounds__(256) void row_finalize(const float* __restrict__ part_denom,
                                                    const int* __restrict__ counts,
                                                    const int* __restrict__ labels,
                                                    float* __restrict__ bsum,
                                                    float* __restrict__ bval) {
    __shared__ float s4[4], v4[4];
    const int t = threadIdx.x;
    const int row = blockIdx.x * 256 + t;
    float denom = 0.f;
    for (int k = 0; k < NT; ++k) denom += part_denom[(size_t)k * BSZ + row];
    const bool valid = counts[labels[row]] >= 2;
    float s = valid ? (INV_T + logf(denom + 1e-12f)) : 0.f;
    float v = valid ? 1.f : 0.f;
    #pragma unroll
    for (int m = 32; m >= 1; m >>= 1) { s += __shfl_xor(s, m, 64); v += __shfl_xor(v, m, 64); }
    if ((t & 63) == 0) { s4[t >> 6] = s; v4[t >> 6] = v; }
    __syncthreads();
    if (t == 0) {
        bsum[blockIdx.x] = s4[0] + s4[1] + s4[2] + s4[3];
        bval[blockIdx.x] = v4[0] + v4[1] + v4[2] + v4[3];
    }
}

// ---------- kernel 5: final scalar ----------
__global__ __launch_bounds__(128) void final_reduce(const float* __restrict__ bsum,
                                                    const float* __restrict__ bval,
                                                    const float* __restrict__ cls_val,
                                                    float* __restrict__ out) {
    __shared__ float r2[2], q2[2], p2[2];
    const int t = threadIdx.x;
    float s = (t < 32) ? bsum[t] : 0.f;
    float v = (t < 32) ? bval[t] : 0.f;
    float p = (t < NC) ? cls_val[t] : 0.f;
    #pragma unroll
    for (int m = 32; m >= 1; m >>= 1) {
        s += __shfl_xor(s, m, 64); v += __shfl_xor(v, m, 64); p += __shfl_xor(p, m, 64);
    }
    if ((t & 63) == 0) { r2[t >> 6] = s; q2[t >> 6] = v; p2[t >> 6] = p; }
    __syncthreads();
    if (t == 0) {
        const float S = r2[0] + r2[1], V = q2[0] + q2[1], SP = p2[0] + p2[1];
        out[0] = -(SP - S) / fmaxf(V, 1.f);
    }
}

extern "C" void kernel_launch(void* const* d_in, const int* in_sizes, int n_in,
                              void* d_out, int out_size, void* d_ws, size_t ws_size,
                              hipStream_t stream) {
    const float* feat   = (const float*)d_in[0];
    const int*   labels = (const int*)d_in[1];
    float*       out    = (float*)d_out;

    char* ws = (char*)d_ws;
    uchar*  fnrm8      = (uchar*)ws;   ws += (size_t)BSZ * DD;       // 4 MB fp8
    float*  part_denom = (float*)ws;   ws += (size_t)NT * BSZ * 4;   // 2 MB
    float*  cls_val    = (float*)ws;   ws += NC * 4 + 288;
    int*    counts     = (int*)ws;     ws += NC * 4 + 288;
    float*  bsum       = (float*)ws;   ws += 32 * 4;
    float*  bval       = (float*)ws;   ws += 32 * 4;

    hipLaunchKernelGGL(norm_rows,    dim3(BSZ / 4), dim3(256),  0, stream, feat, fnrm8);
    hipLaunchKernelGGL(gsum,         dim3(NC),      dim3(256),  0, stream,
                       fnrm8, labels, cls_val, counts);
    hipLaunchKernelGGL(supcon_main,  dim3(NBLK),    dim3(256),  0, stream,
                       fnrm8, part_denom);
    hipLaunchKernelGGL(row_finalize, dim3(BSZ/256), dim3(256),  0, stream,
                       part_denom, counts, labels, bsum, bval);
    hipLaunchKernelGGL(final_reduce, dim3(1),       dim3(128),  0, stream,
                       bsum, bval, cls_val, out);
}